// Round 1
// baseline (1838.251 us; speedup 1.0000x reference)
//
#include <hip/hip_runtime.h>
#include <math.h>

#define NN 10000
#define NE 160000
#define MUL 128
#define ADIM 10
#define RADF 8
#define AUG 264
#define HID 64
#define INV_SQRT3 0.57735026918962576f

__device__ __forceinline__ float silu_f(float x){ return x / (1.0f + expf(-x)); }
__device__ __forceinline__ float sigmoid_f(float x){ return 1.0f / (1.0f + expf(-x)); }

// ---------------- K0: src/tgt embeddings (N,10)@(10,128) ----------------
__global__ __launch_bounds__(256) void k_emb(
    const float* __restrict__ attrs, const float* __restrict__ Ws,
    const float* __restrict__ Wt, float* __restrict__ se, float* __restrict__ te){
  int idx = blockIdx.x*256 + threadIdx.x;
  if (idx >= NN*MUL) return;
  int n = idx >> 7, v = idx & 127;
  float as=0.f, at=0.f;
  #pragma unroll
  for (int a=0;a<ADIM;a++){
    float x = attrs[n*ADIM+a];
    as += x*Ws[a*MUL+v];
    at += x*Wt[a*MUL+v];
  }
  se[idx]=as; te[idx]=at;
}

// ---------------- K1: per-node precompute (skip/up/res) ----------------
#define T1 16
__global__ __launch_bounds__(256) void k_node_pre(
    const float* __restrict__ feats,
    const float* __restrict__ Wsk0, const float* __restrict__ Wsk1,
    const float* __restrict__ Wup0, const float* __restrict__ Wup1,
    const float* __restrict__ Wres0, const float* __restrict__ Wres1,
    float* __restrict__ out_sc,
    float* __restrict__ up_s, float* __restrict__ up_v,
    float* __restrict__ res_s, float* __restrict__ res_v){
  __shared__ float lf[T1*512];
  int nbase = blockIdx.x*T1;
  for (int idx=threadIdx.x; idx<T1*128; idx+=256){
    int ln = idx>>7, c4 = idx&127;
    *(float4*)(lf + ln*512 + c4*4) = *(const float4*)(feats + (size_t)(nbase+ln)*512 + c4*4);
  }
  __syncthreads();
  int oc = threadIdx.x & 127, g = threadIdx.x >> 7;
  int j0 = g*(T1/2);
  // scalar-channel matmuls: s @ {W_skip0, W_up0, W_res0(256)}
  float a_sc[T1/2], a_up[T1/2], a_r0[T1/2], a_r1[T1/2];
  #pragma unroll
  for (int j=0;j<T1/2;j++){ a_sc[j]=0.f; a_up[j]=0.f; a_r0[j]=0.f; a_r1[j]=0.f; }
  for (int u=0;u<128;u++){
    float w0=Wsk0[u*128+oc], w1=Wup0[u*128+oc], w2=Wres0[u*256+oc], w3=Wres0[u*256+128+oc];
    #pragma unroll
    for (int j=0;j<T1/2;j++){
      float x = lf[(j0+j)*512 + u];
      a_sc[j] += x*w0; a_up[j] += x*w1; a_r0[j] += x*w2; a_r1[j] += x*w3;
    }
  }
  for (int j=0;j<T1/2;j++){
    int n = nbase + j0 + j;
    out_sc[(size_t)n*512 + oc]      = a_sc[j];
    up_s[n*128 + oc]                = a_up[j];
    res_s[n*256 + oc]               = a_r0[j];
    res_s[n*256 + 128 + oc]         = a_r1[j];
  }
  // vector-channel matmuls: v_i @ {W_skip1, W_up1, W_res1}
  for (int i=0;i<3;i++){
    float b_sc[T1/2], b_up[T1/2], b_rv[T1/2];
    #pragma unroll
    for (int j=0;j<T1/2;j++){ b_sc[j]=0.f; b_up[j]=0.f; b_rv[j]=0.f; }
    for (int u=0;u<128;u++){
      float w0=Wsk1[u*128+oc], w1=Wup1[u*128+oc], w2=Wres1[u*128+oc];
      #pragma unroll
      for (int j=0;j<T1/2;j++){
        float x = lf[(j0+j)*512 + 128 + u*3 + i];
        b_sc[j]+=x*w0; b_up[j]+=x*w1; b_rv[j]+=x*w2;
      }
    }
    for (int j=0;j<T1/2;j++){
      int n = nbase + j0 + j;
      out_sc[(size_t)n*512 + 128 + oc*3 + i] = b_sc[j];
      up_v[(n*3+i)*128 + oc] = b_up[j];
      res_v[(n*3+i)*128 + oc] = b_rv[j];
    }
  }
}

// ---------------- K2: fused edge kernel (MLPs + messages + scatter) ----------------
#define EPB 16
__global__ __launch_bounds__(1024) void k_edge(
    const float* __restrict__ ef, const float* __restrict__ ea, const int* __restrict__ eidx,
    const float* __restrict__ se, const float* __restrict__ te,
    const float* __restrict__ up_s, const float* __restrict__ up_v,
    const float* __restrict__ Wr1, const float* __restrict__ Wr2,
    const float* __restrict__ Wr3, const float* __restrict__ Wr4,
    const float* __restrict__ Wd1, const float* __restrict__ Wd2,
    float* __restrict__ msg_s, float* __restrict__ msg_v, float* __restrict__ density){
  __shared__ float aug[EPB][AUG];
  __shared__ float hb[2][EPB][HID];
  int w = threadIdx.x >> 6, l = threadIdx.x & 63;
  int e = blockIdx.x*EPB + w;
  int snd = eidx[e*2+0], rcv = eidx[e*2+1];
  for (int c=l;c<AUG;c+=64){
    float x;
    if (c < RADF)          x = ef[e*RADF + c];
    else if (c < RADF+MUL) x = se[snd*MUL + (c-RADF)];
    else                   x = te[rcv*MUL + (c-RADF-MUL)];
    aug[w][c] = x;
  }
  __syncthreads();
  // layer1 (rad + den share aug)
  float acc=0.f, accd=0.f;
  for (int u=0;u<AUG;u++){
    float x = aug[w][u];
    acc  += x*Wr1[u*HID+l];
    accd += x*Wd1[u*HID+l];
  }
  acc = silu_f(acc); accd = silu_f(accd);
  // density: d1 @ W_den2 -> tanh(x^2), scatter
  float edp = accd * Wd2[l];
  #pragma unroll
  for (int off=32; off; off>>=1) edp += __shfl_xor(edp, off);
  if (l==0){
    atomicAdd(density + rcv, tanhf(edp*edp));
  }
  hb[0][w][l] = acc;
  __syncthreads();
  acc = 0.f;
  for (int u=0;u<HID;u++) acc += hb[0][w][u]*Wr2[u*HID+l];
  acc = silu_f(acc);
  hb[1][w][l] = acc;
  __syncthreads();
  acc = 0.f;
  for (int u=0;u<HID;u++) acc += hb[1][w][u]*Wr3[u*HID+l];
  acc = silu_f(acc);
  hb[0][w][l] = acc;
  __syncthreads();
  // layer4: lane l owns tpw columns {l, 64+l} in each of wA,wB,wC,wD
  float t0=0,t1=0,t2=0,t3=0,t4=0,t5=0,t6=0,t7=0;
  for (int u=0;u<HID;u++){
    float x = hb[0][w][u];
    const float* wr = Wr4 + u*512;
    t0 += x*wr[l];      t1 += x*wr[64+l];
    t2 += x*wr[128+l];  t3 += x*wr[192+l];
    t4 += x*wr[256+l];  t5 += x*wr[320+l];
    t6 += x*wr[384+l];  t7 += x*wr[448+l];
  }
  float y0 = ea[e*4+0], y10 = ea[e*4+1], y11 = ea[e*4+2], y12 = ea[e*4+3];
  #pragma unroll
  for (int k=0;k<2;k++){
    int u = l + 64*k;
    float wA = k? t1:t0, wB = k? t3:t2, wC = k? t5:t4, wD = k? t7:t6;
    float xs  = up_s[snd*MUL+u];
    float xv0 = up_v[(snd*3+0)*MUL+u];
    float xv1 = up_v[(snd*3+1)*MUL+u];
    float xv2 = up_v[(snd*3+2)*MUL+u];
    float mA = wA*xs*y0;
    float dot = xv0*y10 + xv1*y11 + xv2*y12;
    float mD = wD*dot*INV_SQRT3;
    atomicAdd(&msg_s[rcv*256 + u], mA);
    atomicAdd(&msg_s[rcv*256 + 128 + u], mD);
    float wBxs = wB*xs;
    float wCy0 = wC*y0;
    atomicAdd(&msg_v[(rcv*3+0)*256 + u], wBxs*y10);
    atomicAdd(&msg_v[(rcv*3+1)*256 + u], wBxs*y11);
    atomicAdd(&msg_v[(rcv*3+2)*256 + u], wBxs*y12);
    atomicAdd(&msg_v[(rcv*3+0)*256 + 128 + u], wCy0*xv0);
    atomicAdd(&msg_v[(rcv*3+1)*256 + 128 + u], wCy0*xv1);
    atomicAdd(&msg_v[(rcv*3+2)*256 + 128 + u], wCy0*xv2);
  }
}

// ---------------- K3a: scalar message path ----------------
#define T3 16
__global__ __launch_bounds__(256) void k_node_s(
    const float* __restrict__ msg_s, const float* __restrict__ density,
    const float* __restrict__ res_s,
    const float* __restrict__ Wl10, const float* __restrict__ Wl20,
    const float* __restrict__ alphap, const float* __restrict__ betap,
    float* __restrict__ gate_ws, float* __restrict__ out_msg){
  __shared__ float ms[T3*256];
  __shared__ float sg[T3*256];
  int nbase = blockIdx.x*T3;
  for (int idx=threadIdx.x; idx<T3*256; idx+=256) ms[idx] = msg_s[(size_t)nbase*256 + idx];
  __syncthreads();
  float alpha = alphap[0], beta = betap[0];
  int oc = threadIdx.x; // 0..255
  float acc[T3];
  #pragma unroll
  for (int j=0;j<T3;j++) acc[j]=0.f;
  for (int u=0;u<256;u++){
    float wv = Wl10[u*256+oc];
    #pragma unroll
    for (int j=0;j<T3;j++) acc[j] += ms[j*256+u]*wv;
  }
  for (int j=0;j<T3;j++){
    int n = nbase+j;
    float den = density[n]*beta + alpha*20.0f;
    float v = acc[j]/den + res_s[n*256+oc];
    float r;
    if (oc < 128) r = silu_f(v);
    else { r = sigmoid_f(v); gate_ws[n*128 + (oc-128)] = r; }
    sg[j*256+oc] = r;
  }
  __syncthreads();
  int oc2 = threadIdx.x & 127, g = threadIdx.x >> 7;
  float a2[T3/2];
  #pragma unroll
  for (int j=0;j<T3/2;j++) a2[j]=0.f;
  for (int u=0;u<128;u++){
    float wv = Wl20[u*128+oc2];
    #pragma unroll
    for (int j=0;j<T3/2;j++) a2[j] += sg[(g*(T3/2)+j)*256+u]*wv;
  }
  for (int j=0;j<T3/2;j++){
    int n = nbase + g*(T3/2)+j;
    out_msg[(size_t)n*512 + oc2*4 + 0] = a2[j];
  }
}

// ---------------- K3b: vector message path ----------------
#define T3B 8
__global__ __launch_bounds__(256) void k_node_v(
    const float* __restrict__ msg_v, const float* __restrict__ density,
    const float* __restrict__ res_v, const float* __restrict__ gate_ws,
    const float* __restrict__ Wl11, const float* __restrict__ Wl21,
    const float* __restrict__ alphap, const float* __restrict__ betap,
    float* __restrict__ out_msg){
  __shared__ float mv[T3B*768];
  __shared__ float vec[T3B*384];
  int nbase = blockIdx.x*T3B;
  for (int idx=threadIdx.x; idx<T3B*768; idx+=256) mv[idx] = msg_v[(size_t)nbase*768 + idx];
  __syncthreads();
  float alpha = alphap[0], beta = betap[0];
  int oc = threadIdx.x & 127, g = threadIdx.x >> 7;
  int j0 = g*(T3B/2);
  float acc[T3B/2][3];
  #pragma unroll
  for (int j=0;j<T3B/2;j++){ acc[j][0]=0.f; acc[j][1]=0.f; acc[j][2]=0.f; }
  for (int u=0;u<256;u++){
    float wv = Wl11[u*128+oc];
    #pragma unroll
    for (int j=0;j<T3B/2;j++){
      acc[j][0] += mv[(j0+j)*768 + 0*256 + u]*wv;
      acc[j][1] += mv[(j0+j)*768 + 1*256 + u]*wv;
      acc[j][2] += mv[(j0+j)*768 + 2*256 + u]*wv;
    }
  }
  for (int j=0;j<T3B/2;j++){
    int n = nbase + j0 + j;
    float den = density[n]*beta + alpha*20.0f;
    float gt = gate_ws[n*128+oc];
    #pragma unroll
    for (int i=0;i<3;i++){
      float v = acc[j][i]/den + res_v[(n*3+i)*128+oc];
      vec[(j0+j)*384 + i*128 + oc] = v*gt;
    }
  }
  __syncthreads();
  float a2[T3B/2][3];
  #pragma unroll
  for (int j=0;j<T3B/2;j++){ a2[j][0]=0.f; a2[j][1]=0.f; a2[j][2]=0.f; }
  for (int u=0;u<128;u++){
    float wv = Wl21[u*128+oc];
    #pragma unroll
    for (int j=0;j<T3B/2;j++){
      a2[j][0] += vec[(j0+j)*384 + 0*128 + u]*wv;
      a2[j][1] += vec[(j0+j)*384 + 1*128 + u]*wv;
      a2[j][2] += vec[(j0+j)*384 + 2*128 + u]*wv;
    }
  }
  for (int j=0;j<T3B/2;j++){
    int n = nbase + j0 + j;
    #pragma unroll
    for (int i=0;i<3;i++)
      out_msg[(size_t)n*512 + oc*4 + 1 + i] = a2[j][i];
  }
}

extern "C" void kernel_launch(void* const* d_in, const int* in_sizes, int n_in,
                              void* d_out, int out_size, void* d_ws, size_t ws_size,
                              hipStream_t stream){
  (void)in_sizes; (void)n_in; (void)out_size; (void)ws_size;
  const float* attrs = (const float*)d_in[0];
  const float* feats = (const float*)d_in[1];
  const float* ea    = (const float*)d_in[2];
  const float* ef    = (const float*)d_in[3];
  const float* Wsrc  = (const float*)d_in[4];
  const float* Wtgt  = (const float*)d_in[5];
  const float* Wup0  = (const float*)d_in[6];
  const float* Wup1  = (const float*)d_in[7];
  const float* Wsk0  = (const float*)d_in[8];
  const float* Wsk1  = (const float*)d_in[9];
  const float* Wres0 = (const float*)d_in[10];
  const float* Wres1 = (const float*)d_in[11];
  const float* Wl10  = (const float*)d_in[12];
  const float* Wl11  = (const float*)d_in[13];
  const float* Wl20  = (const float*)d_in[14];
  const float* Wl21  = (const float*)d_in[15];
  const float* Wr1   = (const float*)d_in[16];
  const float* Wr2   = (const float*)d_in[17];
  const float* Wr3   = (const float*)d_in[18];
  const float* Wr4   = (const float*)d_in[19];
  const float* Wd1   = (const float*)d_in[20];
  const float* Wd2   = (const float*)d_in[21];
  const float* alphap= (const float*)d_in[22];
  const float* betap = (const float*)d_in[23];
  const int*   eidx  = (const int*)d_in[24];

  float* ws = (float*)d_ws;
  float* msg_s   = ws;                    // NN*256
  float* msg_v   = msg_s + (size_t)NN*256; // NN*768
  float* density = msg_v + (size_t)NN*768; // NN
  float* se      = density + NN;           // NN*128
  float* te      = se + (size_t)NN*128;    // NN*128
  float* up_s    = te + (size_t)NN*128;    // NN*128
  float* up_v    = up_s + (size_t)NN*128;  // NN*384
  float* res_s   = up_v + (size_t)NN*384;  // NN*256
  float* res_v   = res_s + (size_t)NN*256; // NN*384
  float* gate    = res_v + (size_t)NN*384; // NN*128

  float* out_msg = (float*)d_out;               // NN*128*4
  float* out_sc  = out_msg + (size_t)NN*512;    // NN*512

  hipMemsetAsync(msg_s, 0, (size_t)NN*(256+768+1)*sizeof(float), stream);

  k_emb<<<(NN*MUL+255)/256, 256, 0, stream>>>(attrs, Wsrc, Wtgt, se, te);
  k_node_pre<<<NN/T1, 256, 0, stream>>>(feats, Wsk0, Wsk1, Wup0, Wup1, Wres0, Wres1,
                                        out_sc, up_s, up_v, res_s, res_v);
  k_edge<<<NE/EPB, 1024, 0, stream>>>(ef, ea, eidx, se, te, up_s, up_v,
                                      Wr1, Wr2, Wr3, Wr4, Wd1, Wd2,
                                      msg_s, msg_v, density);
  k_node_s<<<NN/T3, 256, 0, stream>>>(msg_s, density, res_s, Wl10, Wl20,
                                      alphap, betap, gate, out_msg);
  k_node_v<<<NN/T3B, 256, 0, stream>>>(msg_v, density, res_v, gate, Wl11, Wl21,
                                       alphap, betap, out_msg);
}

// Round 2
// 763.445 us; speedup vs baseline: 2.4078x; 2.4078x over previous
//
#include <hip/hip_runtime.h>
#include <math.h>

#define NN 10000
#define NE 160000
#define MUL 128
#define ADIM 10
#define RADF 8
#define HID 64
#define INV_SQRT3 0.57735026918962576f
#define NCHUNK 4
#define NPC 2500           // nodes per chunk
#define CAP 44032          // max edges per chunk buffer (mean 40000, +20 sigma)

typedef __attribute__((ext_vector_type(8))) short bf16x8;
typedef __attribute__((ext_vector_type(4))) float f32x4;

__device__ __forceinline__ float silu_f(float x){ return x / (1.0f + __expf(-x)); }
__device__ __forceinline__ float sigmoid_f(float x){ return 1.0f / (1.0f + __expf(-x)); }
__device__ __forceinline__ unsigned short f2b(float f){
  union{float f; unsigned u;} v; v.f=f;
  unsigned r = (v.u + 0x7fffu + ((v.u>>16)&1u))>>16;
  return (unsigned short)r;
}
__device__ __forceinline__ float b2f(unsigned short h){
  union{unsigned u; float f;} v; v.u = ((unsigned)h)<<16; return v.f;
}

// ---------------- K0: src/tgt embeddings (N,10)@(10,128) -> bf16 ----------------
__global__ __launch_bounds__(256) void k_emb(
    const float* __restrict__ attrs, const float* __restrict__ Ws,
    const float* __restrict__ Wt, unsigned short* __restrict__ se, unsigned short* __restrict__ te){
  int idx = blockIdx.x*256 + threadIdx.x;
  if (idx >= NN*MUL) return;
  int n = idx >> 7, v = idx & 127;
  float as=0.f, at=0.f;
  #pragma unroll
  for (int a=0;a<ADIM;a++){
    float x = attrs[n*ADIM+a];
    as += x*Ws[a*MUL+v];
    at += x*Wt[a*MUL+v];
  }
  se[idx]=f2b(as); te[idx]=f2b(at);
}

// ---------------- K1: per-node precompute (skip/up/res) ----------------
#define T1 16
__global__ __launch_bounds__(256) void k_node_pre(
    const float* __restrict__ feats,
    const float* __restrict__ Wsk0, const float* __restrict__ Wsk1,
    const float* __restrict__ Wup0, const float* __restrict__ Wup1,
    const float* __restrict__ Wres0, const float* __restrict__ Wres1,
    float* __restrict__ out_sc,
    unsigned short* __restrict__ up_s, unsigned short* __restrict__ up_v,
    float* __restrict__ res_s, float* __restrict__ res_v){
  __shared__ float lf[T1*512];
  int nbase = blockIdx.x*T1;
  for (int idx=threadIdx.x; idx<T1*128; idx+=256){
    int ln = idx>>7, c4 = idx&127;
    *(float4*)(lf + ln*512 + c4*4) = *(const float4*)(feats + (size_t)(nbase+ln)*512 + c4*4);
  }
  __syncthreads();
  int oc = threadIdx.x & 127, g = threadIdx.x >> 7;
  int j0 = g*(T1/2);
  float a_sc[T1/2], a_up[T1/2], a_r0[T1/2], a_r1[T1/2];
  #pragma unroll
  for (int j=0;j<T1/2;j++){ a_sc[j]=0.f; a_up[j]=0.f; a_r0[j]=0.f; a_r1[j]=0.f; }
  for (int u=0;u<128;u++){
    float w0=Wsk0[u*128+oc], w1=Wup0[u*128+oc], w2=Wres0[u*256+oc], w3=Wres0[u*256+128+oc];
    #pragma unroll
    for (int j=0;j<T1/2;j++){
      float x = lf[(j0+j)*512 + u];
      a_sc[j] += x*w0; a_up[j] += x*w1; a_r0[j] += x*w2; a_r1[j] += x*w3;
    }
  }
  for (int j=0;j<T1/2;j++){
    int n = nbase + j0 + j;
    out_sc[(size_t)n*512 + oc]  = a_sc[j];
    up_s[n*128 + oc]            = f2b(a_up[j]);
    res_s[n*256 + oc]           = a_r0[j];
    res_s[n*256 + 128 + oc]     = a_r1[j];
  }
  for (int i=0;i<3;i++){
    float b_sc[T1/2], b_up[T1/2], b_rv[T1/2];
    #pragma unroll
    for (int j=0;j<T1/2;j++){ b_sc[j]=0.f; b_up[j]=0.f; b_rv[j]=0.f; }
    for (int u=0;u<128;u++){
      float w0=Wsk1[u*128+oc], w1=Wup1[u*128+oc], w2=Wres1[u*128+oc];
      #pragma unroll
      for (int j=0;j<T1/2;j++){
        float x = lf[(j0+j)*512 + 128 + u*3 + i];
        b_sc[j]+=x*w0; b_up[j]+=x*w1; b_rv[j]+=x*w2;
      }
    }
    for (int j=0;j<T1/2;j++){
      int n = nbase + j0 + j;
      out_sc[(size_t)n*512 + 128 + oc*3 + i] = b_sc[j];
      up_v[((size_t)n*3+i)*128 + oc] = f2b(b_up[j]);
      res_v[((size_t)n*3+i)*128 + oc] = b_rv[j];
    }
  }
}

// ---------------- weight prep: transpose + bf16 cast, K-padded ----------------
__global__ __launch_bounds__(256) void k_prep(
    const float* __restrict__ Wr1, const float* __restrict__ Wd1,
    const float* __restrict__ Wr2, const float* __restrict__ Wr3,
    const float* __restrict__ Wr4,
    unsigned short* __restrict__ WTr1, unsigned short* __restrict__ WTd1,
    unsigned short* __restrict__ WTr2, unsigned short* __restrict__ WTr3,
    unsigned short* __restrict__ WTr4){
  int idx = blockIdx.x*256 + threadIdx.x;
  if (idx < 18432){
    int n = idx/288, k = idx - n*288;
    WTr1[idx] = (k<264)? f2b(Wr1[k*64+n]) : (unsigned short)0;
  } else if (idx < 36864){
    int j = idx-18432; int n=j/288, k=j-n*288;
    WTd1[j] = (k<264)? f2b(Wd1[k*64+n]) : (unsigned short)0;
  } else if (idx < 40960){
    int j = idx-36864; int n=j>>6, k=j&63;
    WTr2[j] = f2b(Wr2[k*64+n]);
  } else if (idx < 45056){
    int j = idx-40960; int n=j>>6, k=j&63;
    WTr3[j] = f2b(Wr3[k*64+n]);
  } else if (idx < 77824){
    int j = idx-45056; int n=j>>6, k=j&63;
    WTr4[j] = f2b(Wr4[k*512+n]);
  }
}

// ---------------- CSR build ----------------
__global__ __launch_bounds__(256) void k_deg(const int* __restrict__ eidx, int* __restrict__ deg){
  int i = blockIdx.x*256+threadIdx.x;
  if (i<NE) atomicAdd(&deg[eidx[2*i+1]],1);
}
__global__ __launch_bounds__(256) void k_scan(const int* __restrict__ deg, int* __restrict__ offsets){
  __shared__ int part[256];
  int t = threadIdx.x; int base = t*40;
  int s=0;
  for (int k=0;k<40;k++){ int idx=base+k; if (idx<NN) s+=deg[idx]; }
  part[t]=s; __syncthreads();
  if (t==0){ int run=0; for (int i=0;i<256;i++){ int v=part[i]; part[i]=run; run+=v; } }
  __syncthreads();
  int run = part[t];
  for (int k=0;k<40;k++){
    int idx=base+k;
    if (idx<=NN) offsets[idx]=run;
    if (idx<NN) run+=deg[idx];
  }
}
__global__ __launch_bounds__(256) void k_fill(const int* __restrict__ eidx, const int* __restrict__ offsets,
                                              int* __restrict__ cursor, int* __restrict__ elist){
  int i = blockIdx.x*256+threadIdx.x;
  if (i<NE){ int r = eidx[2*i+1]; int p = atomicAdd(&cursor[r],1); elist[offsets[r]+p]=i; }
}

// ---------------- K2: batched MFMA edge MLP -> tpw (bf16) + edge density ----------------
__global__ __launch_bounds__(256) void k_tpw(
    const int* __restrict__ elist, const int* __restrict__ eidx,
    const float* __restrict__ ef, const float* __restrict__ ea,
    const unsigned short* __restrict__ se, const unsigned short* __restrict__ te,
    const unsigned short* __restrict__ WTr1, const unsigned short* __restrict__ WTd1,
    const unsigned short* __restrict__ WTr2, const unsigned short* __restrict__ WTr3,
    const unsigned short* __restrict__ WTr4, const float* __restrict__ Wd2,
    const int* __restrict__ offsets, int nstart, int nend,
    unsigned short* __restrict__ tpw, float4* __restrict__ ybuf,
    int* __restrict__ sndbuf, float* __restrict__ densbuf){
  __shared__ unsigned short aug[64][296];   // 264 used, padded to 288 zeros (K=9x32)
  __shared__ unsigned short hA[64][72];
  __shared__ unsigned short hB[64][72];     // also reused as per-wave out staging
  __shared__ int s_e[64], s_snd[64], s_rcv[64];
  int ebase = offsets[nstart];
  int eend  = min(offsets[nend], ebase + CAP);
  int i0 = ebase + blockIdx.x*64;
  if (i0 >= eend) return;
  int nrows = min(64, eend - i0);
  int tid = threadIdx.x;
  int w = tid>>6, l = tid&63;
  if (tid < 64){
    int ii = min(i0 + tid, eend-1);
    int e = elist[ii];
    s_e[tid]=e;
    int sn = eidx[2*e], rc = eidx[2*e+1];
    s_snd[tid]=sn; s_rcv[tid]=rc;
    if (tid < nrows){
      int li = i0 - ebase + tid;
      sndbuf[li] = sn;
      ybuf[li] = ((const float4*)ea)[e];
    }
  }
  __syncthreads();
  { // stage aug: 4 threads per edge row, 66 cols each
    int r = tid>>2, q = tid&3;
    int e = s_e[r], sn = s_snd[r], rc = s_rcv[r];
    for (int c=q*66; c<q*66+66; ++c){
      unsigned short v;
      if (c < 8)        v = f2b(ef[e*8 + c]);
      else if (c < 136) v = se[sn*128 + (c-8)];
      else              v = te[rc*128 + (c-136)];
      aug[r][c] = v;
    }
    if (q==3){ for (int c=264;c<296;++c) aug[r][c]=0; }
  }
  __syncthreads();
  int m0 = w*16;
  int lr = l&15, lg = l>>4;
  // ---- layer1 (rad) + den1, K=288 ----
  f32x4 acc[4], accd[4];
  #pragma unroll
  for (int nt=0;nt<4;nt++){ acc[nt]=(f32x4)(0.f); accd[nt]=(f32x4)(0.f); }
  for (int kb=0;kb<9;kb++){
    bf16x8 a = *(const bf16x8*)&aug[m0+lr][kb*32 + lg*8];
    #pragma unroll
    for (int nt=0;nt<4;nt++){
      bf16x8 b  = *(const bf16x8*)&WTr1[(nt*16+lr)*288 + kb*32 + lg*8];
      bf16x8 bd = *(const bf16x8*)&WTd1[(nt*16+lr)*288 + kb*32 + lg*8];
      acc[nt]  = __builtin_amdgcn_mfma_f32_16x16x32_bf16(a, b,  acc[nt],  0,0,0);
      accd[nt] = __builtin_amdgcn_mfma_f32_16x16x32_bf16(a, bd, accd[nt], 0,0,0);
    }
  }
  float d0=0,d1=0,d2=0,d3=0;
  #pragma unroll
  for (int nt=0;nt<4;nt++){
    float wd2v = Wd2[nt*16+lr];
    #pragma unroll
    for (int r=0;r<4;r++){
      hA[m0+lg*4+r][nt*16+lr] = f2b(silu_f(acc[nt][r]));
      float sv = silu_f(accd[nt][r]) * wd2v;
      if (r==0) d0+=sv; else if (r==1) d1+=sv; else if (r==2) d2+=sv; else d3+=sv;
    }
  }
  #pragma unroll
  for (int m=1;m<16;m<<=1){
    d0 += __shfl_xor(d0, m); d1 += __shfl_xor(d1, m);
    d2 += __shfl_xor(d2, m); d3 += __shfl_xor(d3, m);
  }
  if (lr < 4){
    float dv = (lr==0)?d0:(lr==1)?d1:(lr==2)?d2:d3;
    int row = m0 + lg*4 + lr;
    if (row < nrows) densbuf[i0 - ebase + row] = tanhf(dv*dv);
  }
  __syncthreads();
  // ---- layer2: hA -> hB ----
  #pragma unroll
  for (int nt=0;nt<4;nt++) acc[nt]=(f32x4)(0.f);
  for (int kb=0;kb<2;kb++){
    bf16x8 a = *(const bf16x8*)&hA[m0+lr][kb*32 + lg*8];
    #pragma unroll
    for (int nt=0;nt<4;nt++){
      bf16x8 b = *(const bf16x8*)&WTr2[(nt*16+lr)*64 + kb*32 + lg*8];
      acc[nt] = __builtin_amdgcn_mfma_f32_16x16x32_bf16(a, b, acc[nt], 0,0,0);
    }
  }
  __syncthreads();
  #pragma unroll
  for (int nt=0;nt<4;nt++)
    #pragma unroll
    for (int r=0;r<4;r++)
      hB[m0+lg*4+r][nt*16+lr] = f2b(silu_f(acc[nt][r]));
  __syncthreads();
  // ---- layer3: hB -> hA ----
  #pragma unroll
  for (int nt=0;nt<4;nt++) acc[nt]=(f32x4)(0.f);
  for (int kb=0;kb<2;kb++){
    bf16x8 a = *(const bf16x8*)&hB[m0+lr][kb*32 + lg*8];
    #pragma unroll
    for (int nt=0;nt<4;nt++){
      bf16x8 b = *(const bf16x8*)&WTr3[(nt*16+lr)*64 + kb*32 + lg*8];
      acc[nt] = __builtin_amdgcn_mfma_f32_16x16x32_bf16(a, b, acc[nt], 0,0,0);
    }
  }
  __syncthreads();
  #pragma unroll
  for (int nt=0;nt<4;nt++)
    #pragma unroll
    for (int r=0;r<4;r++)
      hA[m0+lg*4+r][nt*16+lr] = f2b(silu_f(acc[nt][r]));
  __syncthreads();
  // ---- layer4 (no activation), N=512 in 8 chunks of 64, restage via hB for coalesced out ----
  int li0 = i0 - ebase + m0;
  for (int g=0; g<8; g++){
    f32x4 a4[4];
    #pragma unroll
    for (int nt=0;nt<4;nt++) a4[nt]=(f32x4)(0.f);
    for (int kb=0;kb<2;kb++){
      bf16x8 a = *(const bf16x8*)&hA[m0+lr][kb*32 + lg*8];
      #pragma unroll
      for (int nt=0;nt<4;nt++){
        bf16x8 b = *(const bf16x8*)&WTr4[(g*64+nt*16+lr)*64 + kb*32 + lg*8];
        a4[nt] = __builtin_amdgcn_mfma_f32_16x16x32_bf16(a, b, a4[nt], 0,0,0);
      }
    }
    #pragma unroll
    for (int nt=0;nt<4;nt++)
      #pragma unroll
      for (int r=0;r<4;r++)
        hB[m0+lg*4+r][nt*16+lr] = f2b(a4[nt][r]);
    __syncthreads();
    {
      int row = l>>2, seg = l&3;
      if (m0 + row < nrows){
        const uint4* srcp = (const uint4*)&hB[m0+row][seg*16];
        uint4 v0 = srcp[0], v1 = srcp[1];
        uint4* dst = (uint4*)&tpw[((size_t)(li0+row)*8 + g)*64 + seg*16];
        dst[0]=v0; dst[1]=v1;
      }
    }
    __syncthreads();
  }
}

// ---------------- K3: CSR gather (no atomics) ----------------
__global__ __launch_bounds__(256) void k_gather(
    const unsigned short* __restrict__ tpw, const float4* __restrict__ ybuf,
    const int* __restrict__ sndbuf, const float* __restrict__ densbuf,
    const unsigned short* __restrict__ up_s, const unsigned short* __restrict__ up_v,
    const int* __restrict__ offsets, int nstart,
    float* __restrict__ msg_s, float* __restrict__ msg_v, float* __restrict__ density){
  int w = threadIdx.x>>6, l = threadIdx.x&63;
  int n = nstart + blockIdx.x*4 + w;
  if (n >= NN) return;
  int ebase = offsets[nstart];
  int s0 = offsets[n], s1 = offsets[n+1];
  float mA0=0,mA1=0,mD0=0,mD1=0;
  float mB00=0,mB01=0,mB10=0,mB11=0,mB20=0,mB21=0;
  float mC00=0,mC01=0,mC10=0,mC11=0,mC20=0,mC21=0;
  float dsum=0;
  for (int i=s0;i<s1;++i){
    int li = i - ebase;
    int sn = sndbuf[li];
    float4 y = ybuf[li];
    dsum += densbuf[li];
    const unsigned short* tp = tpw + (size_t)li*512;
    float wA0=b2f(tp[l]),     wA1=b2f(tp[64+l]);
    float wB0=b2f(tp[128+l]), wB1=b2f(tp[192+l]);
    float wC0=b2f(tp[256+l]), wC1=b2f(tp[320+l]);
    float wD0=b2f(tp[384+l]), wD1=b2f(tp[448+l]);
    const unsigned short* us = up_s + (size_t)sn*128;
    float xs0=b2f(us[l]), xs1=b2f(us[64+l]);
    const unsigned short* uv = up_v + (size_t)sn*384;
    float xv00=b2f(uv[l]),     xv01=b2f(uv[64+l]);
    float xv10=b2f(uv[128+l]), xv11=b2f(uv[192+l]);
    float xv20=b2f(uv[256+l]), xv21=b2f(uv[320+l]);
    mA0 += wA0*xs0*y.x; mA1 += wA1*xs1*y.x;
    float dot0 = xv00*y.y + xv10*y.z + xv20*y.w;
    float dot1 = xv01*y.y + xv11*y.z + xv21*y.w;
    mD0 += wD0*dot0; mD1 += wD1*dot1;
    float b0 = wB0*xs0, b1 = wB1*xs1;
    mB00 += b0*y.y; mB01 += b1*y.y;
    mB10 += b0*y.z; mB11 += b1*y.z;
    mB20 += b0*y.w; mB21 += b1*y.w;
    float c0 = wC0*y.x, c1 = wC1*y.x;
    mC00 += c0*xv00; mC01 += c1*xv01;
    mC10 += c0*xv10; mC11 += c1*xv11;
    mC20 += c0*xv20; mC21 += c1*xv21;
  }
  float* ms = msg_s + (size_t)n*256;
  ms[l]=mA0; ms[64+l]=mA1; ms[128+l]=mD0*INV_SQRT3; ms[192+l]=mD1*INV_SQRT3;
  float* mv = msg_v + (size_t)n*768;
  mv[l]=mB00;     mv[64+l]=mB01;  mv[128+l]=mC00; mv[192+l]=mC01;
  mv[256+l]=mB10; mv[320+l]=mB11; mv[384+l]=mC10; mv[448+l]=mC11;
  mv[512+l]=mB20; mv[576+l]=mB21; mv[640+l]=mC20; mv[704+l]=mC21;
  if (l==0) density[n]=dsum;
}

// ---------------- K4a: scalar message path ----------------
#define T3 16
__global__ __launch_bounds__(256) void k_node_s(
    const float* __restrict__ msg_s, const float* __restrict__ density,
    const float* __restrict__ res_s,
    const float* __restrict__ Wl10, const float* __restrict__ Wl20,
    const float* __restrict__ alphap, const float* __restrict__ betap,
    float* __restrict__ gate_ws, float* __restrict__ out_msg){
  __shared__ float ms[T3*256];
  __shared__ float sg[T3*256];
  int nbase = blockIdx.x*T3;
  for (int idx=threadIdx.x; idx<T3*256; idx+=256) ms[idx] = msg_s[(size_t)nbase*256 + idx];
  __syncthreads();
  float alpha = alphap[0], beta = betap[0];
  int oc = threadIdx.x;
  float acc[T3];
  #pragma unroll
  for (int j=0;j<T3;j++) acc[j]=0.f;
  for (int u=0;u<256;u++){
    float wv = Wl10[u*256+oc];
    #pragma unroll
    for (int j=0;j<T3;j++) acc[j] += ms[j*256+u]*wv;
  }
  for (int j=0;j<T3;j++){
    int n = nbase+j;
    float den = density[n]*beta + alpha*20.0f;
    float v = acc[j]/den + res_s[n*256+oc];
    float r;
    if (oc < 128) r = silu_f(v);
    else { r = sigmoid_f(v); gate_ws[n*128 + (oc-128)] = r; }
    sg[j*256+oc] = r;
  }
  __syncthreads();
  int oc2 = threadIdx.x & 127, g = threadIdx.x >> 7;
  float a2[T3/2];
  #pragma unroll
  for (int j=0;j<T3/2;j++) a2[j]=0.f;
  for (int u=0;u<128;u++){
    float wv = Wl20[u*128+oc2];
    #pragma unroll
    for (int j=0;j<T3/2;j++) a2[j] += sg[(g*(T3/2)+j)*256+u]*wv;
  }
  for (int j=0;j<T3/2;j++){
    int n = nbase + g*(T3/2)+j;
    out_msg[(size_t)n*512 + oc2*4 + 0] = a2[j];
  }
}

// ---------------- K4b: vector message path ----------------
#define T3B 8
__global__ __launch_bounds__(256) void k_node_v(
    const float* __restrict__ msg_v, const float* __restrict__ density,
    const float* __restrict__ res_v, const float* __restrict__ gate_ws,
    const float* __restrict__ Wl11, const float* __restrict__ Wl21,
    const float* __restrict__ alphap, const float* __restrict__ betap,
    float* __restrict__ out_msg){
  __shared__ float mv[T3B*768];
  __shared__ float vec[T3B*384];
  int nbase = blockIdx.x*T3B;
  for (int idx=threadIdx.x; idx<T3B*768; idx+=256) mv[idx] = msg_v[(size_t)nbase*768 + idx];
  __syncthreads();
  float alpha = alphap[0], beta = betap[0];
  int oc = threadIdx.x & 127, g = threadIdx.x >> 7;
  int j0 = g*(T3B/2);
  float acc[T3B/2][3];
  #pragma unroll
  for (int j=0;j<T3B/2;j++){ acc[j][0]=0.f; acc[j][1]=0.f; acc[j][2]=0.f; }
  for (int u=0;u<256;u++){
    float wv = Wl11[u*128+oc];
    #pragma unroll
    for (int j=0;j<T3B/2;j++){
      acc[j][0] += mv[(j0+j)*768 + 0*256 + u]*wv;
      acc[j][1] += mv[(j0+j)*768 + 1*256 + u]*wv;
      acc[j][2] += mv[(j0+j)*768 + 2*256 + u]*wv;
    }
  }
  for (int j=0;j<T3B/2;j++){
    int n = nbase + j0 + j;
    float den = density[n]*beta + alpha*20.0f;
    float gt = gate_ws[n*128+oc];
    #pragma unroll
    for (int i=0;i<3;i++){
      float v = acc[j][i]/den + res_v[((size_t)n*3+i)*128+oc];
      vec[(j0+j)*384 + i*128 + oc] = v*gt;
    }
  }
  __syncthreads();
  float a2[T3B/2][3];
  #pragma unroll
  for (int j=0;j<T3B/2;j++){ a2[j][0]=0.f; a2[j][1]=0.f; a2[j][2]=0.f; }
  for (int u=0;u<128;u++){
    float wv = Wl21[u*128+oc];
    #pragma unroll
    for (int j=0;j<T3B/2;j++){
      a2[j][0] += vec[(j0+j)*384 + 0*128 + u]*wv;
      a2[j][1] += vec[(j0+j)*384 + 1*128 + u]*wv;
      a2[j][2] += vec[(j0+j)*384 + 2*128 + u]*wv;
    }
  }
  for (int j=0;j<T3B/2;j++){
    int n = nbase + j0 + j;
    #pragma unroll
    for (int i=0;i<3;i++)
      out_msg[(size_t)n*512 + oc*4 + 1 + i] = a2[j][i];
  }
}

extern "C" void kernel_launch(void* const* d_in, const int* in_sizes, int n_in,
                              void* d_out, int out_size, void* d_ws, size_t ws_size,
                              hipStream_t stream){
  (void)in_sizes; (void)n_in; (void)out_size; (void)ws_size;
  const float* attrs = (const float*)d_in[0];
  const float* feats = (const float*)d_in[1];
  const float* ea    = (const float*)d_in[2];
  const float* ef    = (const float*)d_in[3];
  const float* Wsrc  = (const float*)d_in[4];
  const float* Wtgt  = (const float*)d_in[5];
  const float* Wup0  = (const float*)d_in[6];
  const float* Wup1  = (const float*)d_in[7];
  const float* Wsk0  = (const float*)d_in[8];
  const float* Wsk1  = (const float*)d_in[9];
  const float* Wres0 = (const float*)d_in[10];
  const float* Wres1 = (const float*)d_in[11];
  const float* Wl10  = (const float*)d_in[12];
  const float* Wl11  = (const float*)d_in[13];
  const float* Wl20  = (const float*)d_in[14];
  const float* Wl21  = (const float*)d_in[15];
  const float* Wr1   = (const float*)d_in[16];
  const float* Wr2   = (const float*)d_in[17];
  const float* Wr3   = (const float*)d_in[18];
  const float* Wr4   = (const float*)d_in[19];
  const float* Wd1   = (const float*)d_in[20];
  const float* Wd2   = (const float*)d_in[21];
  const float* alphap= (const float*)d_in[22];
  const float* betap = (const float*)d_in[23];
  const int*   eidx  = (const int*)d_in[24];

  char* p = (char*)d_ws;
  auto alloc = [&](size_t bytes)->char*{ char* r=p; p += (bytes+255)&~(size_t)255; return r; };
  unsigned short* tpw  = (unsigned short*)alloc((size_t)CAP*512*2);
  float*  msg_s   = (float*)alloc((size_t)NN*256*4);
  float*  msg_v   = (float*)alloc((size_t)NN*768*4);
  float*  res_s   = (float*)alloc((size_t)NN*256*4);
  float*  res_v   = (float*)alloc((size_t)NN*384*4);
  float*  gate    = (float*)alloc((size_t)NN*128*4);
  float*  density = (float*)alloc((size_t)NN*4);
  float4* ybuf    = (float4*)alloc((size_t)CAP*16);
  float*  densbuf = (float*)alloc((size_t)CAP*4);
  int*    sndbuf  = (int*)alloc((size_t)CAP*4);
  unsigned short* se16 = (unsigned short*)alloc((size_t)NN*128*2);
  unsigned short* te16 = (unsigned short*)alloc((size_t)NN*128*2);
  unsigned short* up_s16 = (unsigned short*)alloc((size_t)NN*128*2);
  unsigned short* up_v16 = (unsigned short*)alloc((size_t)NN*384*2);
  unsigned short* WTr1 = (unsigned short*)alloc(18432*2);
  unsigned short* WTd1 = (unsigned short*)alloc(18432*2);
  unsigned short* WTr2 = (unsigned short*)alloc(4096*2);
  unsigned short* WTr3 = (unsigned short*)alloc(4096*2);
  unsigned short* WTr4 = (unsigned short*)alloc(32768*2);
  int* deg     = (int*)alloc(10240*4);
  int* cursor  = (int*)alloc(10240*4);
  int* offsets = (int*)alloc(10256*4);
  int* elist   = (int*)alloc((size_t)NE*4);

  float* out_msg = (float*)d_out;               // NN*512 (message col 0..3 interleaved)
  float* out_sc  = out_msg + (size_t)NN*512;    // NN*512

  hipMemsetAsync(deg, 0, 2*10240*sizeof(int), stream);  // deg + cursor (adjacent)

  k_prep<<<304, 256, 0, stream>>>(Wr1, Wd1, Wr2, Wr3, Wr4, WTr1, WTd1, WTr2, WTr3, WTr4);
  k_emb<<<(NN*MUL+255)/256, 256, 0, stream>>>(attrs, Wsrc, Wtgt, se16, te16);
  k_node_pre<<<NN/T1, 256, 0, stream>>>(feats, Wsk0, Wsk1, Wup0, Wup1, Wres0, Wres1,
                                        out_sc, up_s16, up_v16, res_s, res_v);
  k_deg<<<(NE+255)/256, 256, 0, stream>>>(eidx, deg);
  k_scan<<<1, 256, 0, stream>>>(deg, offsets);
  k_fill<<<(NE+255)/256, 256, 0, stream>>>(eidx, offsets, cursor, elist);

  for (int c=0; c<NCHUNK; ++c){
    k_tpw<<<CAP/64, 256, 0, stream>>>(elist, eidx, ef, ea, se16, te16,
                                      WTr1, WTd1, WTr2, WTr3, WTr4, Wd2,
                                      offsets, c*NPC, (c+1)*NPC,
                                      tpw, ybuf, sndbuf, densbuf);
    k_gather<<<NPC/4, 256, 0, stream>>>(tpw, ybuf, sndbuf, densbuf, up_s16, up_v16,
                                        offsets, c*NPC, msg_s, msg_v, density);
  }

  k_node_s<<<NN/T3, 256, 0, stream>>>(msg_s, density, res_s, Wl10, Wl20,
                                      alphap, betap, gate, out_msg);
  k_node_v<<<NN/T3B, 256, 0, stream>>>(msg_v, density, res_v, gate, Wl11, Wl21,
                                       alphap, betap, out_msg);
}